// Round 3
// baseline (38685.019 us; speedup 1.0000x reference)
//
#include <hip/hip_runtime.h>
#include <math.h>

#define B_     2048
#define L_     10
#define D_     512
#define H_     8
#define V_     1974
#define DI_    2048
#define NL_    6
#define BOARD_ 70
#define ROWS_  (B_ * L_)            /* 20480 */
#define SQRT_D 22.627416997969522f

// ---------------------------------------------------------------------------
// Embedding: X[b,l,:] = emb[moves[b,l],:]*sqrt(D) + pos[l,:]
// ---------------------------------------------------------------------------
__global__ __launch_bounds__(256)
void embed_k(const int* __restrict__ moves, const float* __restrict__ emb,
             const float* __restrict__ pos, float* __restrict__ X)
{
    int idx = blockIdx.x * 256 + threadIdx.x;
    if (idx >= ROWS_ * D_) return;
    int d  = idx & 511;
    int bl = idx >> 9;
    int l  = bl % L_;
    int mv = moves[bl];
    X[idx] = emb[mv * D_ + d] * SQRT_D + pos[l * D_ + d];
}

// ---------------------------------------------------------------------------
// LayerNorm over D=512 (f32). One wave per row, 4 rows/block.
// ---------------------------------------------------------------------------
__global__ __launch_bounds__(256)
void ln_k(const float* __restrict__ X, const float* __restrict__ g,
          const float* __restrict__ bta, float* __restrict__ Y, int rows)
{
    int wave = threadIdx.x >> 6;
    int lane = threadIdx.x & 63;
    int row  = blockIdx.x * 4 + wave;
    if (row >= rows) return;
    const float* x = X + (size_t)row * D_;
    float4 t0 = *(const float4*)&x[lane * 8];
    float4 t1 = *(const float4*)&x[lane * 8 + 4];
    float v[8] = { t0.x, t0.y, t0.z, t0.w, t1.x, t1.y, t1.z, t1.w };
    float s1 = 0.f, s2 = 0.f;
    #pragma unroll
    for (int q = 0; q < 8; q++) { s1 += v[q]; s2 += v[q] * v[q]; }
    #pragma unroll
    for (int off = 32; off; off >>= 1) {
        s1 += __shfl_xor(s1, off);
        s2 += __shfl_xor(s2, off);
    }
    float m   = s1 * (1.f / D_);
    float var = s2 * (1.f / D_) - m * m;
    float r   = 1.0f / sqrtf(var + 1e-5f);
    float* y = Y + (size_t)row * D_;
    #pragma unroll
    for (int q = 0; q < 8; q++) {
        int d = lane * 8 + q;
        y[d] = (v[q] - m) * r * g[d] + bta[d];
    }
}

// ---------------------------------------------------------------------------
// Tiled f32 GEMM: C(MxN) = A(MxK) @ B(KxN) [+bias][relu][+resid]
// BM=BN=128, BK=8, 256 threads, 8x8 per thread.
// ---------------------------------------------------------------------------
template<bool BIAS, bool RELU, bool RESID>
__global__ __launch_bounds__(256)
void gemm_k(const float* __restrict__ A, const float* __restrict__ Bw,
            const float* __restrict__ bias, const float* __restrict__ resid,
            float* __restrict__ C, int M, int N, int K)
{
    __shared__ float As[8][128];
    __shared__ float Bs[8][128];
    const int tid = threadIdx.x;
    const int tx = tid & 15, ty = tid >> 4;
    const int m0 = blockIdx.y * 128, n0 = blockIdx.x * 128;
    float acc[8][8] = {};
    const int arow = tid >> 1;        // 0..127
    const int akk  = (tid & 1) * 4;   // 0 or 4
    const int brow = tid >> 5;        // 0..7
    const int bcol = (tid & 31) * 4;  // 0..124
    const int am   = m0 + arow;

    for (int k0 = 0; k0 < K; k0 += 8) {
        float a4[4];
        if (am < M) {
            // K is a multiple of 8 -> row start 32B aligned; akk*4 in {0,16}
            const float* ap = A + (size_t)am * K + k0 + akk;
            float4 t = *(const float4*)ap;
            a4[0] = t.x; a4[1] = t.y; a4[2] = t.z; a4[3] = t.w;
        } else { a4[0] = a4[1] = a4[2] = a4[3] = 0.f; }
        #pragma unroll
        for (int q = 0; q < 4; q++) As[akk + q][arow] = a4[q];

        {
            const int nb = n0 + bcol;
            const float* bp = Bw + (size_t)(k0 + brow) * N + nb;
            float b4[4];
            if (nb + 3 < N) {
                // N may be odd*2 (1974): rows only 8B aligned -> use float2 pairs
                float2 u0 = *(const float2*)bp;
                float2 u1 = *(const float2*)(bp + 2);
                b4[0] = u0.x; b4[1] = u0.y; b4[2] = u1.x; b4[3] = u1.y;
            } else {
                #pragma unroll
                for (int q = 0; q < 4; q++) b4[q] = (nb + q < N) ? bp[q] : 0.f;
            }
            #pragma unroll
            for (int q = 0; q < 4; q++) Bs[brow][bcol + q] = b4[q];
        }
        __syncthreads();

        #pragma unroll
        for (int kk = 0; kk < 8; kk++) {
            float4 a0 = *(const float4*)&As[kk][ty * 8];
            float4 a1 = *(const float4*)&As[kk][ty * 8 + 4];
            float4 b0 = *(const float4*)&Bs[kk][tx * 8];
            float4 b1 = *(const float4*)&Bs[kk][tx * 8 + 4];
            float av[8] = {a0.x,a0.y,a0.z,a0.w,a1.x,a1.y,a1.z,a1.w};
            float bv[8] = {b0.x,b0.y,b0.z,b0.w,b1.x,b1.y,b1.z,b1.w};
            #pragma unroll
            for (int i = 0; i < 8; i++)
                #pragma unroll
                for (int j = 0; j < 8; j++)
                    acc[i][j] += av[i] * bv[j];
        }
        __syncthreads();
    }

    #pragma unroll
    for (int i = 0; i < 8; i++) {
        int m = m0 + ty * 8 + i;
        if (m >= M) continue;
        #pragma unroll
        for (int j = 0; j < 8; j++) {
            int n = n0 + tx * 8 + j;
            if (n >= N) continue;
            float v = acc[i][j];
            if (BIAS)  v += bias[n];
            if (RELU)  v = fmaxf(v, 0.f);
            if (RESID) v += resid[(size_t)m * N + n];
            C[(size_t)m * N + n] = v;
        }
    }
}

// ---------------------------------------------------------------------------
// Self-attention: one block per batch, all 8 heads. Lq=Lk=10, causal+len mask.
// Qb: global (ROWS,512). KVP: chunk-local (chunk_rows,1024). O: global (ROWS,512).
// ---------------------------------------------------------------------------
__global__ __launch_bounds__(256)
void self_attn_k(const float* __restrict__ Qb, const float* __restrict__ KVP,
                 const int* __restrict__ lengths, float* __restrict__ O, int b0)
{
    __shared__ float qs[L_ * D_];
    __shared__ float ks[L_ * D_];
    __shared__ float vs[L_ * D_];
    __shared__ float sc[H_ * L_ * L_];
    int bl  = blockIdx.x;
    int b   = b0 + bl;
    int tid = threadIdx.x;
    int len = lengths[b];

    for (int p = tid; p < L_ * D_; p += 256) {
        int row = p >> 9, col = p & 511;
        qs[p] = Qb[((size_t)(b * L_ + row)) * D_ + col];
        ks[p] = KVP[((size_t)(bl * L_ + row)) * 1024 + col];
        vs[p] = KVP[((size_t)(bl * L_ + row)) * 1024 + 512 + col];
    }
    __syncthreads();

    for (int p = tid; p < H_ * L_ * L_; p += 256) {
        int h = p / (L_ * L_), r = p % (L_ * L_), i = r / L_, j = r % L_;
        float s = -1e30f;
        if (j <= i && j < len) {
            const float* qq = &qs[i * D_ + h * 64];
            const float* kk = &ks[j * D_ + h * 64];
            float d = 0.f;
            #pragma unroll
            for (int d0 = 0; d0 < 64; d0++) d += qq[d0] * kk[d0];
            s = d * 0.125f;
        }
        sc[p] = s;
    }
    __syncthreads();

    if (tid < H_ * L_) {
        int base = tid * L_;
        float mx = -1e30f;
        for (int j = 0; j < L_; j++) mx = fmaxf(mx, sc[base + j]);
        float sum = 0.f;
        for (int j = 0; j < L_; j++) { float e = expf(sc[base + j] - mx); sc[base + j] = e; sum += e; }
        float inv = 1.f / sum;
        for (int j = 0; j < L_; j++) sc[base + j] *= inv;
    }
    __syncthreads();

    for (int p = tid; p < L_ * D_; p += 256) {
        int i = p >> 9, col = p & 511, h = col >> 6;
        float o = 0.f;
        #pragma unroll
        for (int j = 0; j < L_; j++) o += sc[(h * L_ + i) * L_ + j] * vs[j * D_ + col];
        O[((size_t)(b * L_ + i)) * D_ + col] = o;
    }
}

// ---------------------------------------------------------------------------
// Cross-attention: one block per (local batch, head). Lq=10, Lk=70, no mask.
// ---------------------------------------------------------------------------
__global__ __launch_bounds__(256)
void cross_attn_k(const float* __restrict__ Qb, const float* __restrict__ KVP,
                  float* __restrict__ O, int b0)
{
    __shared__ float qs[L_ * 64];
    __shared__ float ks[BOARD_ * 64];
    __shared__ float vs[BOARD_ * 64];
    __shared__ float sc[L_ * BOARD_];
    int blk = blockIdx.x;
    int bl  = blk >> 3;
    int h   = blk & 7;
    int b   = b0 + bl;
    int tid = threadIdx.x;

    for (int p = tid; p < L_ * 64; p += 256) {
        int i = p >> 6, d = p & 63;
        qs[p] = Qb[((size_t)(b * L_ + i)) * D_ + h * 64 + d];
    }
    for (int p = tid; p < BOARD_ * 64; p += 256) {
        int j = p >> 6, d = p & 63;
        size_t kr = (size_t)(bl * BOARD_ + j);
        ks[p] = KVP[kr * 1024 + h * 64 + d];
        vs[p] = KVP[kr * 1024 + 512 + h * 64 + d];
    }
    __syncthreads();

    for (int p = tid; p < L_ * BOARD_; p += 256) {
        int i = p / BOARD_, j = p % BOARD_;
        float d = 0.f;
        #pragma unroll
        for (int d0 = 0; d0 < 64; d0++) d += qs[i * 64 + d0] * ks[j * 64 + d0];
        sc[p] = d * 0.125f;
    }
    __syncthreads();

    if (tid < L_) {
        float mx = -1e30f;
        for (int j = 0; j < BOARD_; j++) mx = fmaxf(mx, sc[tid * BOARD_ + j]);
        float sum = 0.f;
        for (int j = 0; j < BOARD_; j++) {
            float e = expf(sc[tid * BOARD_ + j] - mx);
            sc[tid * BOARD_ + j] = e; sum += e;
        }
        float inv = 1.f / sum;
        for (int j = 0; j < BOARD_; j++) sc[tid * BOARD_ + j] *= inv;
    }
    __syncthreads();

    for (int p = tid; p < L_ * 64; p += 256) {
        int i = p >> 6, d = p & 63;
        float o = 0.f;
        for (int j = 0; j < BOARD_; j++) o += sc[i * BOARD_ + j] * vs[j * 64 + d];
        O[((size_t)(b * L_ + i)) * D_ + h * 64 + d] = o;
    }
}

// ---------------------------------------------------------------------------
// Host-side orchestration.
// d_out (f32, 40.4M elems = 161.7 MB): X @0 | Q @10.49M | U @20.97M (<=18.35M)
// d_ws: XN (41.9 MB).
// Final vocab GEMM reads only XN and overwrites all of d_out last.
// ---------------------------------------------------------------------------
extern "C" void kernel_launch(void* const* d_in, const int* in_sizes, int n_in,
                              void* d_out, int out_size, void* d_ws, size_t ws_size,
                              hipStream_t stream)
{
    (void)in_sizes; (void)n_in; (void)out_size; (void)ws_size;
    const int*   moves   = (const int*)d_in[0];
    const int*   lengths = (const int*)d_in[1];
    const float* boards  = (const float*)d_in[2];
    const float* emb     = (const float*)d_in[3];
    const float* pos     = (const float*)d_in[4];
    const float* sa_ln_g = (const float*)d_in[5];
    const float* sa_ln_b = (const float*)d_in[6];
    const float* sa_wq   = (const float*)d_in[7];
    const float* sa_bq   = (const float*)d_in[8];
    const float* sa_wkv  = (const float*)d_in[9];
    const float* sa_bkv  = (const float*)d_in[10];
    const float* sa_wo   = (const float*)d_in[11];
    const float* sa_bo   = (const float*)d_in[12];
    const float* ca_ln_g = (const float*)d_in[13];
    const float* ca_ln_b = (const float*)d_in[14];
    const float* ca_wq   = (const float*)d_in[15];
    const float* ca_bq   = (const float*)d_in[16];
    const float* ca_wkv  = (const float*)d_in[17];
    const float* ca_bkv  = (const float*)d_in[18];
    const float* ca_wo   = (const float*)d_in[19];
    const float* ca_bo   = (const float*)d_in[20];
    const float* ff_ln_g = (const float*)d_in[21];
    const float* ff_ln_b = (const float*)d_in[22];
    const float* ff_w1   = (const float*)d_in[23];
    const float* ff_b1   = (const float*)d_in[24];
    const float* ff_w2   = (const float*)d_in[25];
    const float* ff_b2   = (const float*)d_in[26];
    const float* fin_g   = (const float*)d_in[27];
    const float* fin_b   = (const float*)d_in[28];
    const float* fc_w    = (const float*)d_in[29];
    const float* fc_b    = (const float*)d_in[30];

    float* X  = (float*)d_out;             // 10.49M elems
    float* Q  = X + (size_t)ROWS_ * D_;    // 10.49M elems
    float* U  = Q + (size_t)ROWS_ * D_;    // <= 18.35M elems (fits: 39.3M <= 40.4M)
    float* XN = (float*)d_ws;              // 10.49M elems

    const int lnGrid = ROWS_ / 4;

    embed_k<<<(ROWS_ * D_ + 255) / 256, 256, 0, stream>>>(moves, emb, pos, X);

    for (int i = 0; i < NL_; i++) {
        // ---------------- self-attention ----------------
        ln_k<<<lnGrid, 256, 0, stream>>>(X, sa_ln_g + i * D_, sa_ln_b + i * D_, XN, ROWS_);
        gemm_k<true, false, false><<<dim3(4, 160), 256, 0, stream>>>(
            XN, sa_wq + (size_t)i * D_ * 512, sa_bq + i * 512, nullptr, Q,
            ROWS_, 512, D_);
        for (int c = 0; c < 2; c++) {                 // 1024 batches / chunk
            const int RB = 1024, RR = RB * L_;        // 10240 rows -> U = 10.49M elems
            gemm_k<true, false, false><<<dim3(8, RR / 128), 256, 0, stream>>>(
                XN + (size_t)c * RR * D_, sa_wkv + (size_t)i * D_ * 1024,
                sa_bkv + i * 1024, nullptr, U, RR, 1024, D_);
            self_attn_k<<<RB, 256, 0, stream>>>(Q, U, lengths, XN, c * RB);
        }
        gemm_k<true, false, true><<<dim3(4, 160), 256, 0, stream>>>(
            XN, sa_wo + (size_t)i * 512 * D_, sa_bo + i * D_, X, X,
            ROWS_, D_, 512);

        // ---------------- cross-attention ----------------
        ln_k<<<lnGrid, 256, 0, stream>>>(X, ca_ln_g + i * D_, ca_ln_b + i * D_, XN, ROWS_);
        gemm_k<true, false, false><<<dim3(4, 160), 256, 0, stream>>>(
            XN, ca_wq + (size_t)i * D_ * 512, ca_bq + i * 512, nullptr, Q,
            ROWS_, 512, D_);
        for (int c = 0; c < B_ / 256; c++) {          // 256 batches / chunk
            const int CHB = 256, KR = CHB * BOARD_;   // 17920 rows -> U = 18.35M elems
            gemm_k<true, false, false><<<dim3(8, KR / 128), 256, 0, stream>>>(
                boards + (size_t)c * KR * D_, ca_wkv + (size_t)i * D_ * 1024,
                ca_bkv + i * 1024, nullptr, U, KR, 1024, D_);
            cross_attn_k<<<CHB * H_, 256, 0, stream>>>(Q, U, XN, c * CHB);
        }
        gemm_k<true, false, true><<<dim3(4, 160), 256, 0, stream>>>(
            XN, ca_wo + (size_t)i * 512 * D_, ca_bo + i * D_, X, X,
            ROWS_, D_, 512);

        // ---------------- FFN ----------------
        ln_k<<<lnGrid, 256, 0, stream>>>(X, ff_ln_g + i * D_, ff_ln_b + i * D_, XN, ROWS_);
        for (int rc = 0; rc < 4; rc++) {
            const int RC = ROWS_ / 4;                 // 5120 rows -> U = 10.49M elems
            gemm_k<true, true, false><<<dim3(16, RC / 128), 256, 0, stream>>>(
                XN + (size_t)rc * RC * D_, ff_w1 + (size_t)i * D_ * DI_,
                ff_b1 + i * DI_, nullptr, U, RC, DI_, D_);
            gemm_k<true, false, true><<<dim3(4, RC / 128), 256, 0, stream>>>(
                U, ff_w2 + (size_t)i * DI_ * D_, ff_b2 + i * D_,
                X + (size_t)rc * RC * D_, X + (size_t)rc * RC * D_, RC, D_, DI_);
        }
    }

    // ---------------- final LN + vocab projection ----------------
    ln_k<<<lnGrid, 256, 0, stream>>>(X, fin_g, fin_b, XN, ROWS_);
    gemm_k<true, false, false><<<dim3((V_ + 127) / 128, 160), 256, 0, stream>>>(
        XN, fc_w, fc_b, nullptr, (float*)d_out, ROWS_, V_, D_);
}